// Round 4
// baseline (2751.885 us; speedup 1.0000x reference)
//
#include <hip/hip_runtime.h>
#include <hip/hip_bf16.h>
#include <stdint.h>

// ---------------------------------------------------------------------------
// Attention_53712861003822 : B=4 S=1024 D=4096, HQ=32 HKV=8 HD=128, GQA 4:1
// Round 4: runtime dtype adaptivity. Inputs may be fp32 (reference dtype) or
// bf16 (harness-converted). A device-side probe of hs decides; GEMM staging
// converts fp32->bf16 in-flight, final GEMM writes fp32 or bf16 accordingly.
// Internal pipeline (Q/K/V/P/attn) is bf16 with fp32 accumulation.
// Memory plan: ws[0,32MB)=Qb (attn in-place); d_out[0,8MB)=Kb, [8,16MB)=Vb
// (dead before the final GEMM overwrites d_out).
// ---------------------------------------------------------------------------

typedef __attribute__((ext_vector_type(8))) short s8_t;     // 8 x bf16
typedef __attribute__((ext_vector_type(4))) float f4_t;     // MFMA acc

#define MFMA16(a, b, c) __builtin_amdgcn_mfma_f32_16x16x32_bf16((a), (b), (c), 0, 0, 0)

__device__ __forceinline__ float b2f(unsigned short u) {
  union { unsigned int i; float f; } x; x.i = ((unsigned int)u) << 16; return x.f;
}
__device__ __forceinline__ unsigned short f2b(float f) {
  union { float f; unsigned int i; } x; x.f = f;
  unsigned int r = x.i + 0x7fff + ((x.i >> 16) & 1);   // RNE
  return (unsigned short)(r >> 16);
}

// Probe: interpret first 64 ushorts of p as bf16. Genuine bf16 inputs here are
// all |v| <= ~1. fp32 data's low mantissa halves are ~random 16-bit patterns:
// P(trigger) per sample ~0.4 -> miss probability ~1e-14 over 64.
__device__ __forceinline__ bool probe_is_f32(const void* p) {
  if (!p) return false;
  const unsigned short* u = (const unsigned short*)p;
  bool f = false;
#pragma unroll
  for (int i = 0; i < 64; ++i) {
    const float v = b2f(u[i]);
    f |= !(fabsf(v) < 1e8f);      // catches huge exponents AND NaN
  }
  return f;
}

// 8 consecutive elements starting at elem offset `off` (must be 8-aligned),
// returned as bf16x8. f32=true: read fp32 and round; else raw bf16.
__device__ __forceinline__ s8_t load8(const void* base, size_t off, bool f32) {
  if (f32) {
    const float* p = (const float*)base + off;
    union { s8_t v; unsigned short u[8]; } t;
#pragma unroll
    for (int i = 0; i < 8; ++i) t.u[i] = f2b(p[i]);
    return t.v;
  }
  return *(const s8_t*)((const unsigned short*)base + off);
}

// ---------------------------------------------------------------------------
// C[M,N] = A[M,K] @ B[N,K]^T  (row-major, fp32 acc). A/B fp32-or-bf16 per
// probe; C bf16 (probeC=null) or fp32. 128x128 tile, BK=64, 4 waves x 4x4
// MFMA tiles. LDS [128][72]: 144B row stride -> 2-way bank alias (free).
// ---------------------------------------------------------------------------
__global__ __launch_bounds__(256) void gemm_bt(
    void* __restrict__ C,
    const void* __restrict__ A,
    const void* __restrict__ B,
    int M, int N, int K,
    const void* probeA, const void* probeB, const void* probeC)
{
  constexpr int LP = 72;
  __shared__ unsigned short sA[128 * LP];
  __shared__ unsigned short sB[128 * LP];
  const bool fA = probe_is_f32(probeA);
  const bool fB = probe_is_f32(probeB);
  const bool fC = probe_is_f32(probeC);

  const int tid  = threadIdx.x;
  const int lane = tid & 63;
  const int wv   = tid >> 6;
  const int wr   = (wv >> 1) * 64;
  const int wc   = (wv & 1) * 64;
  const int quad = lane >> 4;
  const int l16  = lane & 15;
  const int m0 = blockIdx.x * 128;
  const int n0 = blockIdx.y * 128;

  f4_t acc[4][4];
#pragma unroll
  for (int i = 0; i < 4; ++i)
#pragma unroll
    for (int j = 0; j < 4; ++j) acc[i][j] = (f4_t){0.f, 0.f, 0.f, 0.f};

  int srow[4], scol[4];
#pragma unroll
  for (int it = 0; it < 4; ++it) {
    const int s = it * 256 + tid;
    srow[it] = s >> 3;
    scol[it] = (s & 7) * 8;
  }

  const int nK = K >> 6;
  for (int kt = 0; kt < nK; ++kt) {
    const int k0 = kt << 6;
    s8_t va[4], vb[4];
#pragma unroll
    for (int it = 0; it < 4; ++it) {
      va[it] = load8(A, (size_t)(m0 + srow[it]) * K + k0 + scol[it], fA);
      vb[it] = load8(B, (size_t)(n0 + srow[it]) * K + k0 + scol[it], fB);
    }
#pragma unroll
    for (int it = 0; it < 4; ++it) {
      *(s8_t*)(&sA[srow[it] * LP + scol[it]]) = va[it];
      *(s8_t*)(&sB[srow[it] * LP + scol[it]]) = vb[it];
    }
    __syncthreads();
#pragma unroll
    for (int kc = 0; kc < 2; ++kc) {
      s8_t af[4], bf[4];
#pragma unroll
      for (int i = 0; i < 4; ++i) {
        af[i] = *(const s8_t*)(&sA[(wr + i * 16 + l16) * LP + (kc * 4 + quad) * 8]);
        bf[i] = *(const s8_t*)(&sB[(wc + i * 16 + l16) * LP + (kc * 4 + quad) * 8]);
      }
#pragma unroll
      for (int i = 0; i < 4; ++i)
#pragma unroll
        for (int j = 0; j < 4; ++j)
          acc[i][j] = MFMA16(af[i], bf[j], acc[i][j]);
    }
    __syncthreads();
  }

  // epilogue: C/D layout col = lane&15, row = quad*4 + reg
#pragma unroll
  for (int i = 0; i < 4; ++i) {
    const int rbase = m0 + wr + i * 16 + quad * 4;
#pragma unroll
    for (int j = 0; j < 4; ++j) {
      const int col = n0 + wc + j * 16 + l16;
#pragma unroll
      for (int rg = 0; rg < 4; ++rg) {
        const size_t idx = (size_t)(rbase + rg) * N + col;
        if (fC) ((float*)C)[idx] = acc[i][j][rg];
        else    ((unsigned short*)C)[idx] = f2b(acc[i][j][rg]);
      }
    }
  }
}

// ---------------------------------------------------------------------------
// RoPE in-place on bf16 X = (B,S,nh,128). cos/sin adaptive (fp32 or bf16).
// Reference: out[j] = x[j]*cos[s,64+j] - x[64+j]*sin[s,64+j], etc.
// ---------------------------------------------------------------------------
__global__ __launch_bounds__(256) void rope_kernel(
    unsigned short* __restrict__ X,
    const void* __restrict__ cosb,
    const void* __restrict__ sinb,
    int log2nh, const void* probe)
{
  const bool f = probe_is_f32(probe);
  const size_t idx = (size_t)blockIdx.x * 256 + threadIdx.x;
  const int j = (int)(idx & 63);
  const size_t row = idx >> 6;                 // (b*S+s)*nh + h
  const int s = (int)((row >> log2nh) & 1023);
  const int ci = s * 128 + 64 + j;
  const float c  = f ? ((const float*)cosb)[ci] : b2f(((const unsigned short*)cosb)[ci]);
  const float sn = f ? ((const float*)sinb)[ci] : b2f(((const unsigned short*)sinb)[ci]);
  unsigned short* p = X + row * 128;
  const float x1 = b2f(p[j]);
  const float x2 = b2f(p[64 + j]);
  p[j]      = f2b(x1 * c - x2 * sn);
  p[64 + j] = f2b(x2 * c + x1 * sn);
}

// ---------------------------------------------------------------------------
// Attention (all-bf16 buffers): one block per (b, h, 16 q-rows), S=1024.
// O may alias Q (in-place): Q tile fully read into LDS before O writes;
// per-block write-set == read-set.
// ---------------------------------------------------------------------------
__global__ __launch_bounds__(256) void attn_kernel(
    unsigned short* O,
    const unsigned short* Q,
    const unsigned short* __restrict__ Kb,
    const unsigned short* __restrict__ Vb)
{
  constexpr int S = 1024, HQ = 32, HKV = 8, HD = 128;
  constexpr int SCP = 1048;
  constexpr int QP  = 152;
  constexpr int VP  = 88;
  constexpr float SCALE = 0.08838834764831845f;  // 1/sqrt(128)
  __shared__ unsigned short sc[16 * SCP];
  __shared__ unsigned short sq[16 * QP];
  __shared__ unsigned short sv[128 * VP];
  __shared__ float s_linv[16];

  const int bid = blockIdx.x;
  const int qt = bid & 63;
  const int h  = (bid >> 6) & 31;
  const int b  = bid >> 11;
  const int kh = h >> 2;
  const int tid  = threadIdx.x;
  const int lane = tid & 63;
  const int wv   = tid >> 6;
  const int quad = lane >> 4;
  const int l16  = lane & 15;

  const unsigned short* Qg = Q  + ((size_t)(b * S + qt * 16) * HQ + h) * HD;
  const unsigned short* Kg = Kb + ((size_t)b * S * HKV + kh) * HD;
  const unsigned short* Vg = Vb + ((size_t)b * S * HKV + kh) * HD;

  {
    const int r = tid >> 4, c = (tid & 15) * 8;
    *(s8_t*)(&sq[r * QP + c]) = *(const s8_t*)(Qg + (size_t)r * (HQ * HD) + c);
  }
  __syncthreads();

  // ---- phase 1: scores ----
#pragma unroll 1
  for (int kt = 0; kt < 16; ++kt) {
    const int ks = wv * 256 + kt * 16;
    f4_t acc = (f4_t){0.f, 0.f, 0.f, 0.f};
#pragma unroll
    for (int kc = 0; kc < 4; ++kc) {
      const s8_t qa = *(const s8_t*)(&sq[l16 * QP + kc * 32 + quad * 8]);
      const s8_t kf = *(const s8_t*)(Kg + (size_t)(ks + l16) * (HKV * HD) + kc * 32 + quad * 8);
      acc = MFMA16(qa, kf, acc);
    }
#pragma unroll
    for (int rg = 0; rg < 4; ++rg)
      sc[(quad * 4 + rg) * SCP + ks + l16] = f2b(acc[rg] * SCALE);
  }
  __syncthreads();

  // ---- phase 2: softmax ----
  {
    const int r = tid >> 4, c0 = tid & 15;
    float mx = -1e30f;
#pragma unroll 4
    for (int u = 0; u < 64; ++u)
      mx = fmaxf(mx, b2f(sc[r * SCP + c0 + u * 16]));
#pragma unroll
    for (int off = 8; off; off >>= 1) mx = fmaxf(mx, __shfl_xor(mx, off, 16));
    float sum = 0.f;
#pragma unroll 4
    for (int u = 0; u < 64; ++u) {
      const int idx = r * SCP + c0 + u * 16;
      const float e = __expf(b2f(sc[idx]) - mx);
      sum += e;
      sc[idx] = f2b(e);
    }
#pragma unroll
    for (int off = 8; off; off >>= 1) sum += __shfl_xor(sum, off, 16);
    if (c0 == 0) s_linv[r] = 1.0f / sum;
  }
  __syncthreads();

  // ---- phase 3: O = P @ V ----
  f4_t oacc[2];
  oacc[0] = (f4_t){0.f, 0.f, 0.f, 0.f};
  oacc[1] = (f4_t){0.f, 0.f, 0.f, 0.f};
#pragma unroll 1
  for (int ck = 0; ck < 16; ++ck) {
    if (ck) __syncthreads();
#pragma unroll
    for (int it = 0; it < 4; ++it) {
      const int s  = it * 256 + tid;
      const int kk = s >> 4;
      const int c  = (s & 15) * 8;
      const s8_t v = *(const s8_t*)(Vg + (size_t)(ck * 64 + kk) * (HKV * HD) + c);
#pragma unroll
      for (int jj = 0; jj < 8; ++jj)
        sv[(c + jj) * VP + kk] = ((const unsigned short*)&v)[jj];
    }
    __syncthreads();
#pragma unroll
    for (int kc = 0; kc < 2; ++kc) {
      const s8_t pa = *(const s8_t*)(&sc[l16 * SCP + ck * 64 + kc * 32 + quad * 8]);
#pragma unroll
      for (int dt = 0; dt < 2; ++dt) {
        const s8_t vf = *(const s8_t*)(&sv[(wv * 32 + dt * 16 + l16) * VP + kc * 32 + quad * 8]);
        oacc[dt] = MFMA16(pa, vf, oacc[dt]);
      }
    }
  }

#pragma unroll
  for (int dt = 0; dt < 2; ++dt)
#pragma unroll
    for (int rg = 0; rg < 4; ++rg) {
      const int r = quad * 4 + rg;
      const int d = wv * 32 + dt * 16 + l16;
      O[((size_t)(b * S + qt * 16 + r) * HQ + h) * HD + d] =
          f2b(oacc[dt][rg] * s_linv[r]);
    }
}

// ---------------------------------------------------------------------------
extern "C" void kernel_launch(void* const* d_in, const int* in_sizes, int n_in,
                              void* d_out, int out_size, void* d_ws, size_t ws_size,
                              hipStream_t stream)
{
  (void)in_sizes; (void)n_in; (void)out_size; (void)ws_size;
  const void* hs   = d_in[0];
  const void* cosb = d_in[1];
  const void* sinb = d_in[2];
  const void* Wq   = d_in[3];
  const void* Wk   = d_in[4];
  const void* Wv   = d_in[5];
  const void* Wo   = d_in[6];

  // Internal bf16 scratch:
  //   Qb : ws[0,32MB)      (attn output in-place)
  //   Kb : d_out[0,8MB), Vb : d_out[8,16MB)  -- dead before final GEMM
  unsigned short* Qb = (unsigned short*)d_ws;
  unsigned short* Kb = (unsigned short*)d_out;
  unsigned short* Vb = (unsigned short*)d_out + (size_t)4194304;

  gemm_bt<<<dim3(32,  8), 256, 0, stream>>>(Kb, hs, Wk, 4096, 1024, 4096, hs, hs, nullptr);
  gemm_bt<<<dim3(32,  8), 256, 0, stream>>>(Vb, hs, Wv, 4096, 1024, 4096, hs, hs, nullptr);
  gemm_bt<<<dim3(32, 32), 256, 0, stream>>>(Qb, hs, Wq, 4096, 4096, 4096, hs, hs, nullptr);
  rope_kernel<<<32768, 256, 0, stream>>>(Qb, cosb, sinb, 5, hs);
  rope_kernel<<< 8192, 256, 0, stream>>>(Kb, cosb, sinb, 3, hs);
  attn_kernel<<<4 * 32 * 64, 256, 0, stream>>>(Qb, Qb, Kb, Vb);
  // final projection: A=Qb (bf16), B=Wo (adaptive), C=d_out (adaptive dtype)
  gemm_bt<<<dim3(32, 32), 256, 0, stream>>>(d_out, Qb, Wo, 4096, 4096, 4096,
                                            nullptr, hs, hs);
}